// Round 1
// baseline (700.688 us; speedup 1.0000x reference)
//
#include <hip/hip_runtime.h>
#include <stdint.h>

#define V 200000
#define E 600000
#define NB1 782          // ceil(V/256) blocks for scan1

using bf16x8_t = __attribute__((ext_vector_type(8))) short;
using f32x4_t  = __attribute__((ext_vector_type(4))) float;

__device__ __forceinline__ unsigned short f2bf(float f) {
  unsigned int u = __float_as_uint(f);
  unsigned int r = (u + 0x7fffu + ((u >> 16) & 1u)) >> 16;   // RNE, no NaN in data
  return (unsigned short)r;
}

// ---------------------------------------------------------------------------
// Fused GEMM: out[V,256] = verts @ w0^T + b0 (fp32)
//             w1out[V,128] = bf16(verts @ w1^T + b1)
// grid (3 n-tiles, 1563 m-tiles), 256 threads (4 waves, 2x2), BM=BN=128, K=256
// staged as 2 x 128 through XOR-swizzled LDS (bf16).
// ---------------------------------------------------------------------------
__global__ __launch_bounds__(256, 2) void gemm_fused(
    const float* __restrict__ verts,
    const float* __restrict__ w0_w, const float* __restrict__ w0_b,
    const float* __restrict__ w1_w, const float* __restrict__ w1_b,
    float* __restrict__ out, unsigned short* __restrict__ w1out)
{
  __shared__ __align__(16) unsigned short As[128 * 128];
  __shared__ __align__(16) unsigned short Bs[128 * 128];

  const int tid  = threadIdx.x;
  const int lane = tid & 63;
  const int wv   = tid >> 6;
  const int wr   = wv >> 1, wc = wv & 1;
  const int bx   = blockIdx.x;            // n-tile: 0,1 -> out cols; 2 -> w1
  const int mBase = blockIdx.y * 128;

  const float4* v4 = (const float4*)verts;                     // row stride 64
  const float4* w4 = (bx < 2) ? ((const float4*)w0_w) + (size_t)(bx * 128) * 64
                              : (const float4*)w1_w;

  f32x4_t acc[4][4];
  #pragma unroll
  for (int m = 0; m < 4; ++m)
    #pragma unroll
    for (int n = 0; n < 4; ++n)
      acc[m][n] = (f32x4_t){0.f, 0.f, 0.f, 0.f};

  for (int kb = 0; kb < 2; ++kb) {
    // ---- stage A (verts, fp32->bf16) and B (weights) into swizzled LDS ----
    #pragma unroll
    for (int i = 0; i < 16; ++i) {
      int f   = i * 256 + tid;            // 0..4095
      int row = f >> 5;                   // 0..127
      int cq  = f & 31;                   // float4 within 128-wide K slice
      int grow = mBase + row; if (grow >= V) grow = V - 1;
      float4 a = v4[(size_t)grow * 64 + kb * 32 + cq];
      float4 b = w4[(size_t)row * 64 + kb * 32 + cq];
      int idx = (row * 128 + cq * 4) ^ ((row & 7) << 3);       // short units
      union { unsigned short us[4]; uint2 d; } pa, pb;
      pa.us[0] = f2bf(a.x); pa.us[1] = f2bf(a.y);
      pa.us[2] = f2bf(a.z); pa.us[3] = f2bf(a.w);
      pb.us[0] = f2bf(b.x); pb.us[1] = f2bf(b.y);
      pb.us[2] = f2bf(b.z); pb.us[3] = f2bf(b.w);
      *(uint2*)&As[idx] = pa.d;
      *(uint2*)&Bs[idx] = pb.d;
    }
    __syncthreads();

    // ---- MFMA over this K half ----
    #pragma unroll
    for (int kk = 0; kk < 4; ++kk) {
      bf16x8_t af[4], bfr[4];
      #pragma unroll
      for (int m = 0; m < 4; ++m) {
        int row = wr * 64 + m * 16 + (lane & 15);
        int idx = (row * 128 + kk * 32 + (lane >> 4) * 8) ^ ((row & 7) << 3);
        af[m] = *(const bf16x8_t*)&As[idx];
      }
      #pragma unroll
      for (int n = 0; n < 4; ++n) {
        int row = wc * 64 + n * 16 + (lane & 15);
        int idx = (row * 128 + kk * 32 + (lane >> 4) * 8) ^ ((row & 7) << 3);
        bfr[n] = *(const bf16x8_t*)&Bs[idx];
      }
      #pragma unroll
      for (int m = 0; m < 4; ++m)
        #pragma unroll
        for (int n = 0; n < 4; ++n)
          acc[m][n] = __builtin_amdgcn_mfma_f32_16x16x32_bf16(
              af[m], bfr[n], acc[m][n], 0, 0, 0);
    }
    __syncthreads();
  }

  // ---- epilogue: C/D layout col = lane&15, row = (lane>>4)*4 + r ----
  const int l15 = lane & 15, lq = lane >> 4;
  if (bx < 2) {
    #pragma unroll
    for (int n = 0; n < 4; ++n) {
      int col = bx * 128 + wc * 64 + n * 16 + l15;
      float bias = w0_b[col];
      #pragma unroll
      for (int m = 0; m < 4; ++m) {
        int rbase = mBase + wr * 64 + m * 16 + lq * 4;
        #pragma unroll
        for (int r = 0; r < 4; ++r) {
          int row = rbase + r;
          if (row < V) out[(size_t)row * 256 + col] = acc[m][n][r] + bias;
        }
      }
    }
  } else {
    #pragma unroll
    for (int n = 0; n < 4; ++n) {
      int col = wc * 64 + n * 16 + l15;          // 0..127
      float bias = w1_b[col];
      #pragma unroll
      for (int m = 0; m < 4; ++m) {
        int rbase = mBase + wr * 64 + m * 16 + lq * 4;
        #pragma unroll
        for (int r = 0; r < 4; ++r) {
          int row = rbase + r;
          if (row < V) w1out[(size_t)row * 128 + col] = f2bf(acc[m][n][r] + bias);
        }
      }
    }
  }
}

// ---------------------------------------------------------------------------
// CSR build
// ---------------------------------------------------------------------------
__global__ void count_deg(const int* __restrict__ edges, int* __restrict__ deg) {
  int i = blockIdx.x * blockDim.x + threadIdx.x;
  if (i >= 2 * E) return;
  int e = i >> 1, half = i & 1;
  int dst = edges[2 * e + half];
  atomicAdd(&deg[dst], 1);
}

__global__ void scan1(const int* __restrict__ deg, int* __restrict__ rowptr,
                      int* __restrict__ bsums) {
  __shared__ int sm[256];
  int i = blockIdx.x * 256 + threadIdx.x;
  int v = (i < V) ? deg[i] : 0;
  sm[threadIdx.x] = v;
  __syncthreads();
  for (int off = 1; off < 256; off <<= 1) {
    int t = (threadIdx.x >= off) ? sm[threadIdx.x - off] : 0;
    __syncthreads();
    sm[threadIdx.x] += t;
    __syncthreads();
  }
  if (i < V) rowptr[i] = sm[threadIdx.x] - v;      // exclusive within block
  if (threadIdx.x == 255) bsums[blockIdx.x] = sm[255];
}

__global__ void scan2(int* __restrict__ bsums) {
  __shared__ int sm[1024];
  int t = threadIdx.x;
  int v = (t < NB1) ? bsums[t] : 0;
  sm[t] = v;
  __syncthreads();
  for (int off = 1; off < 1024; off <<= 1) {
    int x = (t >= off) ? sm[t - off] : 0;
    __syncthreads();
    sm[t] += x;
    __syncthreads();
  }
  if (t < NB1) bsums[t] = sm[t] - v;               // exclusive block offsets
}

__global__ void scan3(int* __restrict__ rowptr, const int* __restrict__ bsums,
                      int* __restrict__ cursor) {
  int i = blockIdx.x * 256 + threadIdx.x;
  if (i < V) {
    int r = rowptr[i] + bsums[blockIdx.x];
    rowptr[i] = r;
    cursor[i] = r;
  }
  if (i == 0) rowptr[V] = 2 * E;
}

__global__ void fill_adj(const int* __restrict__ edges, int* __restrict__ cursor,
                         int* __restrict__ adj) {
  int i = blockIdx.x * blockDim.x + threadIdx.x;
  if (i >= 2 * E) return;
  int e = i >> 1, half = i & 1;
  int dst = edges[2 * e + half];
  int src = edges[2 * e + (half ^ 1)];
  int pos = atomicAdd(&cursor[dst], 1);
  adj[pos] = src;
}

// ---------------------------------------------------------------------------
// Gather: one wave per vertex; lane handles out cols {2*lane, 2*lane+1}
// ---------------------------------------------------------------------------
__global__ __launch_bounds__(256) void gather(
    const int* __restrict__ rowptr, const int* __restrict__ adj,
    const unsigned short* __restrict__ w1, float* __restrict__ out)
{
  int w = blockIdx.x * 4 + (threadIdx.x >> 6);
  if (w >= V) return;
  int lane = threadIdx.x & 63;
  int s = rowptr[w], e = rowptr[w + 1];
  float a0 = 0.f, a1 = 0.f;
  const unsigned int* base = (const unsigned int*)w1;   // 64 dwords per row
  for (int j = s; j < e; ++j) {
    int u = adj[j];
    unsigned int d = base[(size_t)u * 64 + lane];
    a0 += __uint_as_float(d << 16);
    a1 += __uint_as_float(d & 0xffff0000u);
  }
  size_t o = (size_t)w * 256 + lane * 2;
  out[o]     += a0;
  out[o + 1] += a1;
}

// ---------------------------------------------------------------------------
extern "C" void kernel_launch(void* const* d_in, const int* in_sizes, int n_in,
                              void* d_out, int out_size, void* d_ws, size_t ws_size,
                              hipStream_t stream)
{
  const float* verts = (const float*)d_in[0];
  const int*   edges = (const int*)d_in[1];
  const float* w0_w  = (const float*)d_in[2];
  const float* w0_b  = (const float*)d_in[3];
  const float* w1_w  = (const float*)d_in[4];
  const float* w1_b  = (const float*)d_in[5];
  float* out = (float*)d_out;
  char*  ws  = (char*)d_ws;

  // workspace layout (bytes), total ~58.5 MB
  unsigned short* w1b = (unsigned short*)(ws);            // V*128*2 = 51,200,000
  int* rowptr = (int*)(ws + 51200000);                    // (V+1)*4
  int* cursor = (int*)(ws + 52000256);                    // V*4
  int* adj    = (int*)(ws + 52800256);                    // 2E*4 = 4,800,000
  int* deg    = (int*)(ws + 57600256);                    // V*4
  int* bsums  = (int*)(ws + 58400256);                    // 1024*4

  hipMemsetAsync(deg, 0, V * sizeof(int), stream);
  count_deg<<<(2 * E + 255) / 256, 256, 0, stream>>>(edges, deg);
  scan1<<<NB1, 256, 0, stream>>>(deg, rowptr, bsums);
  scan2<<<1, 1024, 0, stream>>>(bsums);
  scan3<<<NB1, 256, 0, stream>>>(rowptr, bsums, cursor);
  fill_adj<<<(2 * E + 255) / 256, 256, 0, stream>>>(edges, cursor, adj);

  gemm_fused<<<dim3(3, (V + 127) / 128), 256, 0, stream>>>(
      verts, w0_w, w0_b, w1_w, w1_b, out, w1b);

  gather<<<V / 4, 256, 0, stream>>>(rowptr, adj, w1b, out);
}

// Round 2
// 456.369 us; speedup vs baseline: 1.5354x; 1.5354x over previous
//
#include <hip/hip_runtime.h>
#include <stdint.h>

#define V 200000
#define E 600000
#define NB1 782          // ceil(V/256)

using bf16x8_t = __attribute__((ext_vector_type(8))) short;
using f32x4_t  = __attribute__((ext_vector_type(4))) float;

__device__ __forceinline__ unsigned short f2bf(float f) {
  unsigned int u = __float_as_uint(f);
  return (unsigned short)((u + 0x7fffu + ((u >> 16) & 1u)) >> 16);   // RNE
}

#define GLOAD_LDS16(g, l)                                                      \
  __builtin_amdgcn_global_load_lds(                                            \
      (const __attribute__((address_space(1))) unsigned int*)(g),              \
      (__attribute__((address_space(3))) unsigned int*)(l), 16, 0, 0)

// ---------------------------------------------------------------------------
// prep_w: Wb[384][256] bf16  (rows 0..255 = w0_w, rows 256..383 = w1_w)
// ---------------------------------------------------------------------------
__global__ void prep_w(const float* __restrict__ w0, const float* __restrict__ w1,
                       unsigned short* __restrict__ Wb) {
  int i = blockIdx.x * 256 + threadIdx.x;          // 0..98303
  float v = (i < 65536) ? w0[i] : w1[i - 65536];
  Wb[i] = f2bf(v);
}

// ---------------------------------------------------------------------------
// GEMM: per 128-row M-tile compute all 384 cols.
//   out[V,256] = verts @ w0^T + b0 (fp32),  w1b[V,128] = bf16(verts @ w1^T + b1)
// 512 threads (8 waves, 2M x 4N; wave tile 64x96). K=256 in 4 steps of 64,
// double-buffered LDS (A 2x16KB reg-staged fp32->bf16, B 2x48KB global_load_lds
// with pre-swizzled per-lane source). XOR-swizzle: phys16Bchunk = chunk^(row&7).
// ---------------------------------------------------------------------------
__global__ __launch_bounds__(512, 2) void gemm(
    const float* __restrict__ verts, const unsigned short* __restrict__ Wb,
    const float* __restrict__ w0_b, const float* __restrict__ w1_b,
    float* __restrict__ out, unsigned short* __restrict__ w1b)
{
  __shared__ __align__(16) unsigned short As[2][128 * 64];   // 32 KB
  __shared__ __align__(16) unsigned short Bs[2][384 * 64];   // 96 KB

  const int tid  = threadIdx.x;
  const int lane = tid & 63;
  const int wv   = tid >> 6;          // 0..7
  const int wr   = wv >> 2;           // 0..1 (M half)
  const int wc   = wv & 3;            // 0..3 (N quarter: 96 cols)
  const int mBase = blockIdx.x * 128;

  const int arow = tid >> 4;          // 0..31 (A staging row, +32 per sweep)
  const int ac4  = tid & 15;          // float4 index within 64-K slice

  f32x4_t acc[4][6];
  #pragma unroll
  for (int m = 0; m < 4; ++m)
    #pragma unroll
    for (int n = 0; n < 6; ++n)
      acc[m][n] = (f32x4_t){0.f, 0.f, 0.f, 0.f};

  auto stageB = [&](int b, int kb) {
    #pragma unroll
    for (int i = 0; i < 6; ++i) {
      int r0  = wv * 48 + i * 8;                 // wave-uniform row base
      int row = r0 + (lane >> 3);
      int l   = (lane & 7) ^ (row & 7);          // pre-swizzled source chunk
      const unsigned short* src = Wb + row * 256 + kb * 64 + l * 8;
      unsigned short* dst = &Bs[b][0] + r0 * 64 + lane * 8;  // linear dest
      GLOAD_LDS16(src, dst);
    }
  };
  auto stageA_load = [&](int kb, float4* regs) {
    #pragma unroll
    for (int s = 0; s < 4; ++s) {
      int row = s * 32 + arow;
      int gr = mBase + row; if (gr >= V) gr = V - 1;
      regs[s] = *(const float4*)(verts + (size_t)gr * 256 + kb * 64 + ac4 * 4);
    }
  };
  auto stageA_write = [&](int b, const float4* regs) {
    #pragma unroll
    for (int s = 0; s < 4; ++s) {
      int row  = s * 32 + arow;
      int phys = (ac4 >> 1) ^ (row & 7);
      unsigned short* p = &As[b][0] + row * 64 + phys * 8 + (ac4 & 1) * 4;
      unsigned int lo = (unsigned)f2bf(regs[s].x) | ((unsigned)f2bf(regs[s].y) << 16);
      unsigned int hi = (unsigned)f2bf(regs[s].z) | ((unsigned)f2bf(regs[s].w) << 16);
      uint2 d; d.x = lo; d.y = hi;
      *(uint2*)p = d;
    }
  };

  // prologue: fill buffer 0 with K-step 0
  {
    float4 areg[4];
    stageA_load(0, areg);
    stageB(0, 0);
    stageA_write(0, areg);
  }
  __syncthreads();

  int buf = 0;
  for (int kb = 0; kb < 4; ++kb) {
    float4 anext[4];
    if (kb < 3) {                      // issue next-step loads early (T14)
      stageA_load(kb + 1, anext);
      stageB(buf ^ 1, kb + 1);
    }
    // compute on current buffer
    #pragma unroll
    for (int kk = 0; kk < 2; ++kk) {
      bf16x8_t af[4], bfr[6];
      #pragma unroll
      for (int m = 0; m < 4; ++m) {
        int row  = wr * 64 + m * 16 + (lane & 15);
        int phys = (kk * 4 + (lane >> 4)) ^ (row & 7);
        af[m] = *(const bf16x8_t*)&As[buf][row * 64 + phys * 8];
      }
      #pragma unroll
      for (int n = 0; n < 6; ++n) {
        int row  = wc * 96 + n * 16 + (lane & 15);
        int phys = (kk * 4 + (lane >> 4)) ^ (row & 7);
        bfr[n] = *(const bf16x8_t*)&Bs[buf][row * 64 + phys * 8];
      }
      #pragma unroll
      for (int m = 0; m < 4; ++m)
        #pragma unroll
        for (int n = 0; n < 6; ++n)
          acc[m][n] = __builtin_amdgcn_mfma_f32_16x16x32_bf16(
              af[m], bfr[n], acc[m][n], 0, 0, 0);
    }
    if (kb < 3) stageA_write(buf ^ 1, anext);   // loads long returned by now
    __syncthreads();
    buf ^= 1;
  }

  // epilogue: C/D layout col = lane&15, row = (lane>>4)*4 + r
  const int l15 = lane & 15, lq = lane >> 4;
  #pragma unroll
  for (int n = 0; n < 6; ++n) {
    int col = wc * 96 + n * 16 + l15;            // 0..383 (uniform side of 256 per n)
    bool isOut = col < 256;
    float bias = isOut ? w0_b[col] : w1_b[col - 256];
    #pragma unroll
    for (int m = 0; m < 4; ++m) {
      int rb = mBase + wr * 64 + m * 16 + lq * 4;
      #pragma unroll
      for (int r = 0; r < 4; ++r) {
        int row = rb + r;
        if (row < V) {
          float v = acc[m][n][r] + bias;
          if (isOut) out[(size_t)row * 256 + col] = v;
          else       w1b[(size_t)row * 128 + (col - 256)] = f2bf(v);
        }
      }
    }
  }
}

// ---------------------------------------------------------------------------
// CSR build
// ---------------------------------------------------------------------------
__global__ void count_deg(const int* __restrict__ edges, int* __restrict__ deg) {
  int i = blockIdx.x * blockDim.x + threadIdx.x;
  if (i >= 2 * E) return;
  int e = i >> 1, half = i & 1;
  atomicAdd(&deg[edges[2 * e + half]], 1);
}

__global__ void scan1(const int* __restrict__ deg, int* __restrict__ rowptr,
                      int* __restrict__ bsums) {
  __shared__ int sm[256];
  int i = blockIdx.x * 256 + threadIdx.x;
  int v = (i < V) ? deg[i] : 0;
  sm[threadIdx.x] = v;
  __syncthreads();
  for (int off = 1; off < 256; off <<= 1) {
    int t = (threadIdx.x >= off) ? sm[threadIdx.x - off] : 0;
    __syncthreads();
    sm[threadIdx.x] += t;
    __syncthreads();
  }
  if (i < V) rowptr[i] = sm[threadIdx.x] - v;
  if (threadIdx.x == 255) bsums[blockIdx.x] = sm[255];
}

__global__ void scan2(int* __restrict__ bsums) {
  __shared__ int sm[1024];
  int t = threadIdx.x;
  int v = (t < NB1) ? bsums[t] : 0;
  sm[t] = v;
  __syncthreads();
  for (int off = 1; off < 1024; off <<= 1) {
    int x = (t >= off) ? sm[t - off] : 0;
    __syncthreads();
    sm[t] += x;
    __syncthreads();
  }
  if (t < NB1) bsums[t] = sm[t] - v;
}

__global__ void scan3(int* __restrict__ rowptr, const int* __restrict__ bsums,
                      int* __restrict__ cursor) {
  int i = blockIdx.x * 256 + threadIdx.x;
  if (i < V) {
    int r = rowptr[i] + bsums[blockIdx.x];
    rowptr[i] = r;
    cursor[i] = r;
  }
  if (i == 0) rowptr[V] = 2 * E;
}

__global__ void fill_adj(const int* __restrict__ edges, int* __restrict__ cursor,
                         int* __restrict__ adj) {
  int i = blockIdx.x * blockDim.x + threadIdx.x;
  if (i >= 2 * E) return;
  int e = i >> 1, half = i & 1;
  int dst = edges[2 * e + half];
  int src = edges[2 * e + (half ^ 1)];
  adj[atomicAdd(&cursor[dst], 1)] = src;
}

// ---------------------------------------------------------------------------
// Gather: one wave per vertex; lane covers out cols {2*lane, 2*lane+1}.
// 4-wide batched inner loop for memory-level parallelism.
// ---------------------------------------------------------------------------
__global__ __launch_bounds__(256) void gather(
    const int* __restrict__ rowptr, const int* __restrict__ adj,
    const unsigned short* __restrict__ w1, float* __restrict__ out)
{
  int w = blockIdx.x * 4 + (threadIdx.x >> 6);
  if (w >= V) return;
  int lane = threadIdx.x & 63;
  int s = rowptr[w], e = rowptr[w + 1];
  float a0 = 0.f, a1 = 0.f;
  const unsigned int* base = (const unsigned int*)w1;   // 64 dwords per row
  int j = s;
  for (; j + 4 <= e; j += 4) {
    int u0 = adj[j], u1 = adj[j + 1], u2 = adj[j + 2], u3 = adj[j + 3];
    unsigned d0 = base[(size_t)u0 * 64 + lane];
    unsigned d1 = base[(size_t)u1 * 64 + lane];
    unsigned d2 = base[(size_t)u2 * 64 + lane];
    unsigned d3 = base[(size_t)u3 * 64 + lane];
    a0 += __uint_as_float(d0 << 16) + __uint_as_float(d1 << 16)
        + __uint_as_float(d2 << 16) + __uint_as_float(d3 << 16);
    a1 += __uint_as_float(d0 & 0xffff0000u) + __uint_as_float(d1 & 0xffff0000u)
        + __uint_as_float(d2 & 0xffff0000u) + __uint_as_float(d3 & 0xffff0000u);
  }
  for (; j < e; ++j) {
    unsigned d = base[(size_t)adj[j] * 64 + lane];
    a0 += __uint_as_float(d << 16);
    a1 += __uint_as_float(d & 0xffff0000u);
  }
  float2* o = (float2*)(out + (size_t)w * 256 + lane * 2);
  float2 cur = *o;
  cur.x += a0; cur.y += a1;
  *o = cur;
}

// ---------------------------------------------------------------------------
extern "C" void kernel_launch(void* const* d_in, const int* in_sizes, int n_in,
                              void* d_out, int out_size, void* d_ws, size_t ws_size,
                              hipStream_t stream)
{
  const float* verts = (const float*)d_in[0];
  const int*   edges = (const int*)d_in[1];
  const float* w0_w  = (const float*)d_in[2];
  const float* w0_b  = (const float*)d_in[3];
  const float* w1_w  = (const float*)d_in[4];
  const float* w1_b  = (const float*)d_in[5];
  float* out = (float*)d_out;
  char*  ws  = (char*)d_ws;

  // workspace layout (bytes), total ~58.6 MB
  unsigned short* w1b = (unsigned short*)(ws);            // V*128*2 = 51,200,000
  int* rowptr = (int*)(ws + 51200000);                    // (V+1)*4
  int* cursor = (int*)(ws + 52000256);                    // V*4
  int* adj    = (int*)(ws + 52800256);                    // 2E*4 = 4,800,000
  int* deg    = (int*)(ws + 57600256);                    // V*4
  int* bsums  = (int*)(ws + 58400256);                    // 1024*4
  unsigned short* Wb = (unsigned short*)(ws + 58404352);  // 384*256*2 = 196,608

  hipMemsetAsync(deg, 0, V * sizeof(int), stream);
  prep_w<<<384, 256, 0, stream>>>(w0_w, w1_w, Wb);
  count_deg<<<(2 * E + 255) / 256, 256, 0, stream>>>(edges, deg);
  scan1<<<NB1, 256, 0, stream>>>(deg, rowptr, bsums);
  scan2<<<1, 1024, 0, stream>>>(bsums);
  scan3<<<NB1, 256, 0, stream>>>(rowptr, bsums, cursor);
  fill_adj<<<(2 * E + 255) / 256, 256, 0, stream>>>(edges, cursor, adj);

  gemm<<<(V + 127) / 128, 512, 0, stream>>>(verts, Wb, w0_b, w1_b, out, w1b);

  gather<<<V / 4, 256, 0, stream>>>(rowptr, adj, w1b, out);
}

// Round 3
// 385.009 us; speedup vs baseline: 1.8199x; 1.1853x over previous
//
#include <hip/hip_runtime.h>
#include <stdint.h>

#define V 200000
#define E 600000
#define NB1 782          // ceil(V/256)

using bf16x8_t = __attribute__((ext_vector_type(8))) short;
using f32x4_t  = __attribute__((ext_vector_type(4))) float;

__device__ __forceinline__ unsigned short f2bf(float f) {
  unsigned int u = __float_as_uint(f);
  return (unsigned short)((u + 0x7fffu + ((u >> 16) & 1u)) >> 16);   // RNE
}

// ---------------------------------------------------------------------------
// prep_w2: arrange weights fragment-linear so B MFMA operands are fully
// coalesced 1KB global loads from L2 (no LDS for B at all).
//   o = ((kg*24 + cg)*64 + lane)*8 + e
//   maps to W[c][k], c = cg*16 + (lane&15), k = kg*32 + (lane>>4)*8 + e
//   c in [0,256) -> w0 rows; [256,384) -> w1 rows.
// ---------------------------------------------------------------------------
__global__ void prep_w2(const float* __restrict__ w0, const float* __restrict__ w1,
                        unsigned short* __restrict__ Wb2) {
  int o = blockIdx.x * 256 + threadIdx.x;        // 0..98303
  int kg = o / 12288;
  int r  = o - kg * 12288;
  int cg = r >> 9;
  int r2 = r & 511;
  int lane = r2 >> 3, e = r2 & 7;
  int c = cg * 16 + (lane & 15);
  int k = kg * 32 + (lane >> 4) * 8 + e;
  float v = (c < 256) ? w0[c * 256 + k] : w1[(c - 256) * 256 + k];
  Wb2[o] = f2bf(v);
}

// ---------------------------------------------------------------------------
// GEMM: BM=64, all 384 cols per block. 8 waves, each owns 64 rows x 48 cols.
// A: fp32->bf16 reg-staged into 16KB double-buffered XOR-swizzled LDS.
// B: register loads from fragment-linear Wb2 (L2-resident), barrier-free.
// Grid = V/64 = 3125 exactly; 2 blocks/CU (16 waves) for latency hiding.
// ---------------------------------------------------------------------------
__global__ __launch_bounds__(512, 4) void gemm(
    const float* __restrict__ verts, const unsigned short* __restrict__ Wb2,
    const float* __restrict__ w0_b, const float* __restrict__ w1_b,
    float* __restrict__ out, unsigned short* __restrict__ w1b)
{
  __shared__ __align__(16) unsigned short As[2][64 * 64];   // 16 KB

  const int tid  = threadIdx.x;
  const int lane = tid & 63;
  const int wv   = tid >> 6;            // 0..7 -> cols [wv*48, wv*48+48)
  const int mBase = blockIdx.x * 64;

  // A staging: thread covers row = tid>>3, k-segment (8 floats) = tid&7
  const int srow  = tid >> 3;
  const int skseg = tid & 7;
  const float* vsrc = verts + (size_t)(mBase + srow) * 256 + skseg * 8;
  const int sWoff = srow * 64 + ((skseg ^ (srow & 7)) * 8);   // swizzled LDS short-index

  f32x4_t acc[4][3];
  #pragma unroll
  for (int m = 0; m < 4; ++m)
    #pragma unroll
    for (int n = 0; n < 3; ++n)
      acc[m][n] = (f32x4_t){0.f, 0.f, 0.f, 0.f};

  auto Aload = [&](int kb, float4* a) {
    a[0] = *(const float4*)(vsrc + kb * 64);
    a[1] = *(const float4*)(vsrc + kb * 64 + 4);
  };
  auto Awrite = [&](int b, const float4* a) {
    union { unsigned short us[8]; uint4 q; } p;
    p.us[0] = f2bf(a[0].x); p.us[1] = f2bf(a[0].y);
    p.us[2] = f2bf(a[0].z); p.us[3] = f2bf(a[0].w);
    p.us[4] = f2bf(a[1].x); p.us[5] = f2bf(a[1].y);
    p.us[6] = f2bf(a[1].z); p.us[7] = f2bf(a[1].w);
    *(uint4*)&As[b][sWoff] = p.q;
  };
  auto compute = [&](int b, int kb) {
    #pragma unroll
    for (int kc = 0; kc < 2; ++kc) {
      bf16x8_t af[4], bfr[3];
      #pragma unroll
      for (int m = 0; m < 4; ++m) {
        int row = m * 16 + (lane & 15);
        int seg = (kc * 4 + (lane >> 4)) ^ (row & 7);
        af[m] = *(const bf16x8_t*)&As[b][row * 64 + seg * 8];
      }
      int kg = kb * 2 + kc;
      #pragma unroll
      for (int n = 0; n < 3; ++n) {
        int f = kg * 24 + wv * 3 + n;
        bfr[n] = *(const bf16x8_t*)(Wb2 + (size_t)f * 512 + lane * 8);
      }
      #pragma unroll
      for (int m = 0; m < 4; ++m)
        #pragma unroll
        for (int n = 0; n < 3; ++n)
          acc[m][n] = __builtin_amdgcn_mfma_f32_16x16x32_bf16(
              af[m], bfr[n], acc[m][n], 0, 0, 0);
    }
  };

  // prologue
  {
    float4 a0[2];
    Aload(0, a0);
    Awrite(0, a0);
  }
  __syncthreads();

  int buf = 0;
  #pragma unroll
  for (int kb = 0; kb < 3; ++kb) {
    float4 an[2];
    Aload(kb + 1, an);          // issue early: latency hides under compute
    compute(buf, kb);
    Awrite(buf ^ 1, an);
    __syncthreads();
    buf ^= 1;
  }
  compute(buf, 3);

  // epilogue: C/D layout col = lane&15, row = (lane>>4)*4 + r
  const int l15 = lane & 15, lq = lane >> 4;
  #pragma unroll
  for (int n = 0; n < 3; ++n) {
    int col = wv * 48 + n * 16 + l15;
    if (col < 256) {                       // wave-uniform per n
      float bias = w0_b[col];
      #pragma unroll
      for (int m = 0; m < 4; ++m) {
        int rb = mBase + m * 16 + lq * 4;
        #pragma unroll
        for (int r = 0; r < 4; ++r)
          out[(size_t)(rb + r) * 256 + col] = acc[m][n][r] + bias;
      }
    } else {
      int cc = col - 256;
      float bias = w1_b[cc];
      #pragma unroll
      for (int m = 0; m < 4; ++m) {
        int rb = mBase + m * 16 + lq * 4;
        #pragma unroll
        for (int r = 0; r < 4; ++r)
          w1b[(size_t)(rb + r) * 128 + cc] = f2bf(acc[m][n][r] + bias);
      }
    }
  }
}

// ---------------------------------------------------------------------------
// CSR build
// ---------------------------------------------------------------------------
__global__ void count_deg(const int* __restrict__ edges, int* __restrict__ deg) {
  int i = blockIdx.x * blockDim.x + threadIdx.x;
  if (i >= 2 * E) return;
  int e = i >> 1, half = i & 1;
  atomicAdd(&deg[edges[2 * e + half]], 1);
}

__global__ void scan1(const int* __restrict__ deg, int* __restrict__ rowptr,
                      int* __restrict__ bsums) {
  __shared__ int sm[256];
  int i = blockIdx.x * 256 + threadIdx.x;
  int v = (i < V) ? deg[i] : 0;
  sm[threadIdx.x] = v;
  __syncthreads();
  for (int off = 1; off < 256; off <<= 1) {
    int t = (threadIdx.x >= off) ? sm[threadIdx.x - off] : 0;
    __syncthreads();
    sm[threadIdx.x] += t;
    __syncthreads();
  }
  if (i < V) rowptr[i] = sm[threadIdx.x] - v;
  if (threadIdx.x == 255) bsums[blockIdx.x] = sm[255];
}

__global__ void scan2(int* __restrict__ bsums) {
  __shared__ int sm[1024];
  int t = threadIdx.x;
  int v = (t < NB1) ? bsums[t] : 0;
  sm[t] = v;
  __syncthreads();
  for (int off = 1; off < 1024; off <<= 1) {
    int x = (t >= off) ? sm[t - off] : 0;
    __syncthreads();
    sm[t] += x;
    __syncthreads();
  }
  if (t < NB1) bsums[t] = sm[t] - v;
}

__global__ void scan3(int* __restrict__ rowptr, const int* __restrict__ bsums,
                      int* __restrict__ cursor) {
  int i = blockIdx.x * 256 + threadIdx.x;
  if (i < V) {
    int r = rowptr[i] + bsums[blockIdx.x];
    rowptr[i] = r;
    cursor[i] = r;
  }
  if (i == 0) rowptr[V] = 2 * E;
}

__global__ void fill_adj(const int* __restrict__ edges, int* __restrict__ cursor,
                         int* __restrict__ adj) {
  int i = blockIdx.x * blockDim.x + threadIdx.x;
  if (i >= 2 * E) return;
  int e = i >> 1, half = i & 1;
  int dst = edges[2 * e + half];
  int src = edges[2 * e + (half ^ 1)];
  adj[atomicAdd(&cursor[dst], 1)] = src;
}

// ---------------------------------------------------------------------------
// Gather: one wave per vertex; lane covers out cols {2*lane, 2*lane+1}.
// ---------------------------------------------------------------------------
__global__ __launch_bounds__(256) void gather(
    const int* __restrict__ rowptr, const int* __restrict__ adj,
    const unsigned short* __restrict__ w1, float* __restrict__ out)
{
  int w = blockIdx.x * 4 + (threadIdx.x >> 6);
  if (w >= V) return;
  int lane = threadIdx.x & 63;
  int s = rowptr[w], e = rowptr[w + 1];
  float a0 = 0.f, a1 = 0.f;
  const unsigned int* base = (const unsigned int*)w1;   // 64 dwords per row
  int j = s;
  for (; j + 4 <= e; j += 4) {
    int u0 = adj[j], u1 = adj[j + 1], u2 = adj[j + 2], u3 = adj[j + 3];
    unsigned d0 = base[(size_t)u0 * 64 + lane];
    unsigned d1 = base[(size_t)u1 * 64 + lane];
    unsigned d2 = base[(size_t)u2 * 64 + lane];
    unsigned d3 = base[(size_t)u3 * 64 + lane];
    a0 += __uint_as_float(d0 << 16) + __uint_as_float(d1 << 16)
        + __uint_as_float(d2 << 16) + __uint_as_float(d3 << 16);
    a1 += __uint_as_float(d0 & 0xffff0000u) + __uint_as_float(d1 & 0xffff0000u)
        + __uint_as_float(d2 & 0xffff0000u) + __uint_as_float(d3 & 0xffff0000u);
  }
  for (; j < e; ++j) {
    unsigned d = base[(size_t)adj[j] * 64 + lane];
    a0 += __uint_as_float(d << 16);
    a1 += __uint_as_float(d & 0xffff0000u);
  }
  float2* o = (float2*)(out + (size_t)w * 256 + lane * 2);
  float2 cur = *o;
  cur.x += a0; cur.y += a1;
  *o = cur;
}

// ---------------------------------------------------------------------------
extern "C" void kernel_launch(void* const* d_in, const int* in_sizes, int n_in,
                              void* d_out, int out_size, void* d_ws, size_t ws_size,
                              hipStream_t stream)
{
  const float* verts = (const float*)d_in[0];
  const int*   edges = (const int*)d_in[1];
  const float* w0_w  = (const float*)d_in[2];
  const float* w0_b  = (const float*)d_in[3];
  const float* w1_w  = (const float*)d_in[4];
  const float* w1_b  = (const float*)d_in[5];
  float* out = (float*)d_out;
  char*  ws  = (char*)d_ws;

  // workspace layout (bytes), total ~58.8 MB
  unsigned short* w1b = (unsigned short*)(ws);            // V*128*2 = 51,200,000
  int* rowptr = (int*)(ws + 51200000);                    // (V+1)*4
  int* cursor = (int*)(ws + 52000256);                    // V*4
  int* adj    = (int*)(ws + 52800256);                    // 2E*4 = 4,800,000
  int* deg    = (int*)(ws + 57600256);                    // V*4
  int* bsums  = (int*)(ws + 58400256);                    // 1024*4
  unsigned short* Wb2 = (unsigned short*)(ws + 58404352); // 98304*2*2 = 393,216

  hipMemsetAsync(deg, 0, V * sizeof(int), stream);
  prep_w2<<<384, 256, 0, stream>>>(w0_w, w1_w, Wb2);
  count_deg<<<(2 * E + 255) / 256, 256, 0, stream>>>(edges, deg);
  scan1<<<NB1, 256, 0, stream>>>(deg, rowptr, bsums);
  scan2<<<1, 1024, 0, stream>>>(bsums);
  scan3<<<NB1, 256, 0, stream>>>(rowptr, bsums, cursor);
  fill_adj<<<(2 * E + 255) / 256, 256, 0, stream>>>(edges, cursor, adj);

  gemm<<<(V + 63) / 64, 512, 0, stream>>>(verts, Wb2, w0_b, w1_b, out, w1b);

  gather<<<V / 4, 256, 0, stream>>>(rowptr, adj, w1b, out);
}